// Round 6
// baseline (238.500 us; speedup 1.0000x reference)
//
#include <hip/hip_runtime.h>

#define F_IN   128
#define F_OUT  128

typedef __attribute__((ext_vector_type(8))) short short8;
typedef __attribute__((ext_vector_type(4))) float floatx4;

__device__ __forceinline__ float bf16u_to_f_lo(unsigned int u) {
    union { unsigned int i; float f; } c; c.i = u << 16; return c.f;
}
__device__ __forceinline__ float bf16u_to_f_hi(unsigned int u) {
    union { unsigned int i; float f; } c; c.i = u & 0xffff0000u; return c.f;
}
__device__ __forceinline__ unsigned short f_to_bf16(float f) {
    union { float f; unsigned int i; } c; c.f = f;
    unsigned int u = c.i;
    u += 0x7fffu + ((u >> 16) & 1u);   // round-to-nearest-even
    return (unsigned short)(u >> 16);
}
__device__ __forceinline__ unsigned int pack2(unsigned short a, unsigned short b) {
    return (unsigned int)a | ((unsigned int)b << 16);
}
__device__ __forceinline__ void acc8(float* a, uint4 v) {
    a[0] += bf16u_to_f_lo(v.x); a[1] += bf16u_to_f_hi(v.x);
    a[2] += bf16u_to_f_lo(v.y); a[3] += bf16u_to_f_hi(v.y);
    a[4] += bf16u_to_f_lo(v.z); a[5] += bf16u_to_f_hi(v.z);
    a[6] += bf16u_to_f_lo(v.w); a[7] += bf16u_to_f_hi(v.w);
}

// ---------------------------------------------------------------------------
// prep: zero off[N] AND convert x (fp32) -> x_bf16[N][128] in ws. One launch.
// ---------------------------------------------------------------------------
__global__ __launch_bounds__(256) void prep_kernel(const float* __restrict__ x,
                                                   int* __restrict__ off,
                                                   unsigned short* __restrict__ xb, int N) {
    long tid = (long)blockIdx.x * blockDim.x + threadIdx.x;
    long nconv = (long)N * 32;
    long total = nconv + N;
    long stride = (long)gridDim.x * blockDim.x;
    for (; tid < total; tid += stride) {
        if (tid < nconv) {
            int row = (int)(tid >> 5);
            int seg = (int)(tid & 31);
            float4 v = *(const float4*)(x + (size_t)row * 128 + seg * 4);
            *(ushort4*)(xb + (size_t)row * 128 + seg * 4) =
                make_ushort4(f_to_bf16(v.x), f_to_bf16(v.y), f_to_bf16(v.z), f_to_bf16(v.w));
        } else {
            off[tid - nconv] = 0;
        }
    }
}

// ---------------------------------------------------------------------------
// CSR build. edge_index arrives int32: src = ei[0..E), dst = ei[E..2E).
// ---------------------------------------------------------------------------
__global__ void hist_kernel(const int* __restrict__ src, int* __restrict__ cnt, int E) {
    int e = blockIdx.x * blockDim.x + threadIdx.x;
    if (e < E) atomicAdd(&cnt[src[e]], 1);
}

__global__ __launch_bounds__(256) void chunk_sums_kernel(const int* __restrict__ cnt,
                                                         int* __restrict__ partials, int n) {
    __shared__ int s[256];
    int b = blockIdx.x, t = threadIdx.x;
    int base = b * 1024 + t * 4;
    int sum = 0;
#pragma unroll
    for (int j = 0; j < 4; ++j) {
        int i = base + j;
        if (i < n) sum += cnt[i];
    }
    s[t] = sum;
    __syncthreads();
    for (int d = 128; d > 0; d >>= 1) {
        if (t < d) s[t] += s[t + d];
        __syncthreads();
    }
    if (t == 0) partials[b] = s[0];
}

__global__ __launch_bounds__(128) void scan_partials_kernel(const int* __restrict__ partials,
                                                            int* __restrict__ chunk_off, int nch) {
    __shared__ int s[128];
    int t = threadIdx.x;
    s[t] = (t < nch) ? partials[t] : 0;
    __syncthreads();
    for (int d = 1; d < 128; d <<= 1) {
        int val = s[t];
        int add = (t >= d) ? s[t - d] : 0;
        __syncthreads();
        s[t] = val + add;
        __syncthreads();
    }
    if (t < nch) chunk_off[t] = (t > 0) ? s[t - 1] : 0;
}

__global__ __launch_bounds__(256) void scan_chunks_kernel(int* __restrict__ off,
                                                          const int* __restrict__ chunk_off,
                                                          int n) {
    __shared__ int s[256];
    int b = blockIdx.x, t = threadIdx.x;
    int base = b * 1024 + t * 4;
    int v[4];
#pragma unroll
    for (int j = 0; j < 4; ++j) {
        int i = base + j;
        v[j] = (i < n) ? off[i] : 0;
    }
    int l1 = v[0], l2 = l1 + v[1], l3 = l2 + v[2], tot = l3 + v[3];
    s[t] = tot;
    __syncthreads();
    for (int d = 1; d < 256; d <<= 1) {
        int val = s[t];
        int add = (t >= d) ? s[t - d] : 0;
        __syncthreads();
        s[t] = val + add;
        __syncthreads();
    }
    int thr_excl = ((t > 0) ? s[t - 1] : 0) + chunk_off[b];
    if (base + 0 < n) off[base + 0] = thr_excl;
    if (base + 1 < n) off[base + 1] = thr_excl + l1;
    if (base + 2 < n) off[base + 2] = thr_excl + l2;
    if (base + 3 < n) off[base + 3] = thr_excl + l3;
}

__global__ void fill_kernel(const int* __restrict__ ei, int* __restrict__ off,
                            int* __restrict__ dst_sorted, int E) {
    int e = blockIdx.x * blockDim.x + threadIdx.x;
    if (e < E) {
        int s = ei[e];
        int d = ei[E + e];
        int p = atomicAdd(&off[s], 1);
        dst_sorted[p] = d;
    }
}

// ---------------------------------------------------------------------------
// Fused gather + MFMA GEMM.
//   out[m][n] = sum_k A[m][k]*M[n][k], K=256, A=[agg_bf16 | x_bf16].
//   agg is computed IN REGISTERS: thread (m16,quad) owns A-frags s=0..3
//   (k = s*32+quad*8..+8) of node row m16, i.e. accumulates 4xuint4 (32 fp32)
//   over the node's edge list, reading x_bf16[dst] from ws. x-half frags
//   (s=4..7) load directly from the node's own x_bf16 row. B=[W;B] is
//   converted fp32->bf16 in-kernel and staged in LDS in frag-lane order.
//   4 waves/block, wave = 32 rows (2 groups of 16) x 128 cols; 128 rows/block.
//   No aliasing: reads xb (ws), writes out.
// ---------------------------------------------------------------------------
__global__ __launch_bounds__(256) void gather_gemm_kernel(const float* __restrict__ W,
                                                          const float* __restrict__ Bm,
                                                          const int* __restrict__ off,
                                                          const int* __restrict__ dst_sorted,
                                                          const unsigned short* __restrict__ xb,
                                                          float* __restrict__ out, int N) {
    __shared__ uint4 Bs[4096];  // 64 KB: Bs[(nt*8+s)*64 + lane]
    int t = threadIdx.x;
    int lane = t & 63;
    int w = t >> 6;
    int m16 = lane & 15;
    int quad = lane >> 4;

    // ---- stage B fragments (fp32 -> bf16, frag-lane-major) ----
#pragma unroll
    for (int nt2 = 0; nt2 < 2; ++nt2) {
        int nt = w * 2 + nt2;
        int n = nt * 16 + m16;
#pragma unroll
        for (int s = 0; s < 8; ++s) {
            int kbase = s * 32 + quad * 8;
            const float* srcp = (kbase < 128) ? (W + n * 128 + kbase)
                                              : (Bm + n * 128 + (kbase - 128));
            float4 v0 = *(const float4*)srcp;
            float4 v1 = *(const float4*)(srcp + 4);
            uint4 pk;
            pk.x = pack2(f_to_bf16(v0.x), f_to_bf16(v0.y));
            pk.y = pack2(f_to_bf16(v0.z), f_to_bf16(v0.w));
            pk.z = pack2(f_to_bf16(v1.x), f_to_bf16(v1.y));
            pk.w = pack2(f_to_bf16(v1.z), f_to_bf16(v1.w));
            Bs[(nt * 8 + s) * 64 + lane] = pk;
        }
    }
    __syncthreads();   // only barrier; gather below uses no LDS

    int rowbase = blockIdx.x * 128 + w * 32;
    short8 afrag[2][8];

#pragma unroll
    for (int g = 0; g < 2; ++g) {
        int node = rowbase + g * 16 + m16;
        if (node > N - 1) node = N - 1;  // tail clamp (stores guarded later)
        int start = (node == 0) ? 0 : off[node - 1];
        int end = off[node];
        int deg = end - start;

        float acc[4][8];
#pragma unroll
        for (int s = 0; s < 4; ++s)
#pragma unroll
            for (int j = 0; j < 8; ++j) acc[s][j] = 0.0f;

        int j = start;
        for (; j + 2 <= end; j += 2) {
            int d0 = dst_sorted[j];
            int d1 = dst_sorted[j + 1];
            const char* p0 = (const char*)xb + (size_t)d0 * 256 + quad * 16;
            const char* p1 = (const char*)xb + (size_t)d1 * 256 + quad * 16;
            uint4 a0 = *(const uint4*)(p0);
            uint4 a1 = *(const uint4*)(p0 + 64);
            uint4 a2 = *(const uint4*)(p0 + 128);
            uint4 a3 = *(const uint4*)(p0 + 192);
            uint4 b0 = *(const uint4*)(p1);
            uint4 b1 = *(const uint4*)(p1 + 64);
            uint4 b2 = *(const uint4*)(p1 + 128);
            uint4 b3 = *(const uint4*)(p1 + 192);
            acc8(acc[0], a0); acc8(acc[1], a1); acc8(acc[2], a2); acc8(acc[3], a3);
            acc8(acc[0], b0); acc8(acc[1], b1); acc8(acc[2], b2); acc8(acc[3], b3);
        }
        if (j < end) {
            int d0 = dst_sorted[j];
            const char* p0 = (const char*)xb + (size_t)d0 * 256 + quad * 16;
            uint4 a0 = *(const uint4*)(p0);
            uint4 a1 = *(const uint4*)(p0 + 64);
            uint4 a2 = *(const uint4*)(p0 + 128);
            uint4 a3 = *(const uint4*)(p0 + 192);
            acc8(acc[0], a0); acc8(acc[1], a1); acc8(acc[2], a2); acc8(acc[3], a3);
        }

        float scale = (deg > 0) ? (1.0f / (float)deg) : 1.0f;
#pragma unroll
        for (int s = 0; s < 4; ++s) {
            uint4 pk;
            pk.x = pack2(f_to_bf16(acc[s][0] * scale), f_to_bf16(acc[s][1] * scale));
            pk.y = pack2(f_to_bf16(acc[s][2] * scale), f_to_bf16(acc[s][3] * scale));
            pk.z = pack2(f_to_bf16(acc[s][4] * scale), f_to_bf16(acc[s][5] * scale));
            pk.w = pack2(f_to_bf16(acc[s][6] * scale), f_to_bf16(acc[s][7] * scale));
            afrag[g][s] = *(short8*)&pk;
        }
        // x-half fragments straight from the node's own bf16 row
        const char* q0 = (const char*)xb + (size_t)node * 256 + quad * 16;
#pragma unroll
        for (int s = 0; s < 4; ++s)
            afrag[g][4 + s] = *(const short8*)(q0 + s * 64);
    }

    floatx4 acc[2][8];
#pragma unroll
    for (int g = 0; g < 2; ++g)
#pragma unroll
        for (int nt = 0; nt < 8; ++nt) acc[g][nt] = (floatx4){0.f, 0.f, 0.f, 0.f};

#pragma unroll
    for (int nt = 0; nt < 8; ++nt) {
#pragma unroll
        for (int s = 0; s < 8; ++s) {
            short8 bfrag = *(const short8*)&Bs[(nt * 8 + s) * 64 + lane];
            acc[0][nt] = __builtin_amdgcn_mfma_f32_16x16x32_bf16(afrag[0][s], bfrag, acc[0][nt], 0, 0, 0);
            acc[1][nt] = __builtin_amdgcn_mfma_f32_16x16x32_bf16(afrag[1][s], bfrag, acc[1][nt], 0, 0, 0);
        }
    }

#pragma unroll
    for (int g = 0; g < 2; ++g)
#pragma unroll
        for (int nt = 0; nt < 8; ++nt)
#pragma unroll
            for (int r = 0; r < 4; ++r) {
                int gr = rowbase + g * 16 + quad * 4 + r;
                if (gr < N) out[(size_t)gr * 128 + nt * 16 + m16] = acc[g][nt][r];
            }
}

// ---------------------------------------------------------------------------
// Fallback tier 2: previous in-place path (x_bf16 + agg packed in out rows).
// ---------------------------------------------------------------------------
__global__ void zero_kernel(int* __restrict__ p, long n) {
    long i = (long)blockIdx.x * blockDim.x + threadIdx.x;
    long stride = (long)gridDim.x * blockDim.x;
    for (; i < n; i += stride) p[i] = 0;
}

__global__ __launch_bounds__(256) void convert_x_kernel(const float* __restrict__ x,
                                                        char* __restrict__ outb, int N) {
    long tid = (long)blockIdx.x * blockDim.x + threadIdx.x;
    if (tid >= (long)N * 32) return;
    int row = (int)(tid >> 5);
    int seg = (int)(tid & 31);
    float4 v = *(const float4*)(x + (size_t)row * 128 + seg * 4);
    *(ushort4*)(outb + (size_t)row * 512 + 256 + seg * 8) =
        make_ushort4(f_to_bf16(v.x), f_to_bf16(v.y), f_to_bf16(v.z), f_to_bf16(v.w));
}

__global__ __launch_bounds__(256) void gather_bf16_kernel(const int* __restrict__ off,
                                                          const int* __restrict__ dst_sorted,
                                                          char* __restrict__ outb, int N) {
    int node = blockIdx.x * 16 + (threadIdx.x >> 4);
    int lane = threadIdx.x & 15;
    if (node >= N) return;
    int start = (node == 0) ? 0 : off[node - 1];
    int end = off[node];
    float acc[8];
#pragma unroll
    for (int i = 0; i < 8; ++i) acc[i] = 0.0f;
    const char* xb = outb;
    int j = start;
    for (; j + 2 <= end; j += 2) {
        int d0 = dst_sorted[j];
        int d1 = dst_sorted[j + 1];
        uint4 a = *(const uint4*)(xb + (size_t)d0 * 512 + 256 + lane * 16);
        uint4 b = *(const uint4*)(xb + (size_t)d1 * 512 + 256 + lane * 16);
        acc8(acc, a); acc8(acc, b);
    }
    if (j < end) {
        int d0 = dst_sorted[j];
        uint4 a = *(const uint4*)(xb + (size_t)d0 * 512 + 256 + lane * 16);
        acc8(acc, a);
    }
    int deg = end - start;
    float scale = (deg > 0) ? (1.0f / (float)deg) : 1.0f;
    uint4 pk;
    pk.x = pack2(f_to_bf16(acc[0] * scale), f_to_bf16(acc[1] * scale));
    pk.y = pack2(f_to_bf16(acc[2] * scale), f_to_bf16(acc[3] * scale));
    pk.z = pack2(f_to_bf16(acc[4] * scale), f_to_bf16(acc[5] * scale));
    pk.w = pack2(f_to_bf16(acc[6] * scale), f_to_bf16(acc[7] * scale));
    *(uint4*)(outb + (size_t)node * 512 + lane * 16) = pk;
}

__global__ __launch_bounds__(256) void gemm_mfma_kernel(const float* __restrict__ W,
                                                        const float* __restrict__ Bm,
                                                        float* __restrict__ out, int N) {
    __shared__ uint4 Bs[4096];
    int t = threadIdx.x;
    int lane = t & 63;
    int w = t >> 6;
    int m16 = lane & 15;
    int quad = lane >> 4;
#pragma unroll
    for (int nt2 = 0; nt2 < 2; ++nt2) {
        int nt = w * 2 + nt2;
        int n = nt * 16 + m16;
#pragma unroll
        for (int s = 0; s < 8; ++s) {
            int kbase = s * 32 + quad * 8;
            const float* srcp = (kbase < 128) ? (W + n * 128 + kbase)
                                              : (Bm + n * 128 + (kbase - 128));
            float4 v0 = *(const float4*)srcp;
            float4 v1 = *(const float4*)(srcp + 4);
            uint4 pk;
            pk.x = pack2(f_to_bf16(v0.x), f_to_bf16(v0.y));
            pk.y = pack2(f_to_bf16(v0.z), f_to_bf16(v0.w));
            pk.z = pack2(f_to_bf16(v1.x), f_to_bf16(v1.y));
            pk.w = pack2(f_to_bf16(v1.z), f_to_bf16(v1.w));
            Bs[(nt * 8 + s) * 64 + lane] = pk;
        }
    }
    __syncthreads();

    int rowbase = blockIdx.x * 128 + w * 32;
    short8 afrag[2][8];
#pragma unroll
    for (int g = 0; g < 2; ++g) {
        int arow = rowbase + g * 16 + m16;
        if (arow > N - 1) arow = N - 1;
        const char* ab = (const char*)out + (size_t)arow * 512;
#pragma unroll
        for (int s = 0; s < 8; ++s)
            afrag[g][s] = *(const short8*)(ab + s * 64 + quad * 16);
    }

    floatx4 acc[2][8];
#pragma unroll
    for (int g = 0; g < 2; ++g)
#pragma unroll
        for (int nt = 0; nt < 8; ++nt) acc[g][nt] = (floatx4){0.f, 0.f, 0.f, 0.f};

#pragma unroll
    for (int nt = 0; nt < 8; ++nt) {
#pragma unroll
        for (int s = 0; s < 8; ++s) {
            short8 bfrag = *(const short8*)&Bs[(nt * 8 + s) * 64 + lane];
            acc[0][nt] = __builtin_amdgcn_mfma_f32_16x16x32_bf16(afrag[0][s], bfrag, acc[0][nt], 0, 0, 0);
            acc[1][nt] = __builtin_amdgcn_mfma_f32_16x16x32_bf16(afrag[1][s], bfrag, acc[1][nt], 0, 0, 0);
        }
    }
#pragma unroll
    for (int g = 0; g < 2; ++g)
#pragma unroll
        for (int nt = 0; nt < 8; ++nt)
#pragma unroll
            for (int r = 0; r < 4; ++r) {
                int gr = rowbase + g * 16 + quad * 4 + r;
                if (gr < N) out[(size_t)gr * 128 + nt * 16 + m16] = acc[g][nt][r];
            }
}

// ---------------------------------------------------------------------------

extern "C" void kernel_launch(void* const* d_in, const int* in_sizes, int n_in,
                              void* d_out, int out_size, void* d_ws, size_t ws_size,
                              hipStream_t stream) {
    const float* x = (const float*)d_in[0];
    const int* ei = (const int*)d_in[1];     // int32 per harness contract
    const float* W = (const float*)d_in[2];
    const float* Bm = (const float*)d_in[3];
    float* out = (float*)d_out;

    const int N = in_sizes[0] / F_IN;   // 100000
    const int E = in_sizes[1] / 2;      // 625000
    const int NCHUNK = (N + 1023) / 1024;

    // ws layout: off[N], partials[128], chunk_off[128], dst_sorted[E], x_bf16[N*128]
    int* off        = (int*)d_ws;
    int* partials   = off + N;
    int* chunk_off  = partials + 128;
    int* dst_sorted = chunk_off + 128;
    size_t xb_off   = (((size_t)(N + 256 + E) * sizeof(int)) + 255) & ~(size_t)255;
    unsigned short* xb = (unsigned short*)((char*)d_ws + xb_off);

    const size_t need_fused = xb_off + (size_t)N * 128 * sizeof(unsigned short);
    const size_t need_csr   = ((size_t)N + 256 + (size_t)E) * sizeof(int);

    if (ws_size >= need_fused) {
        // ---- primary: CSR + register-fused gather/MFMA-GEMM (7 launches) ----
        prep_kernel<<<512, 256, 0, stream>>>(x, off, xb, N);
        hist_kernel<<<(E + 255) / 256, 256, 0, stream>>>(ei, off, E);
        chunk_sums_kernel<<<NCHUNK, 256, 0, stream>>>(off, partials, N);
        scan_partials_kernel<<<1, 128, 0, stream>>>(partials, chunk_off, NCHUNK);
        scan_chunks_kernel<<<NCHUNK, 256, 0, stream>>>(off, chunk_off, N);
        fill_kernel<<<(E + 255) / 256, 256, 0, stream>>>(ei, off, dst_sorted, E);
        gather_gemm_kernel<<<(N + 127) / 128, 256, 0, stream>>>(W, Bm, off, dst_sorted, xb, out, N);
    } else if (ws_size >= need_csr) {
        // ---- fallback: round-5 in-place path ----
        zero_kernel<<<256, 256, 0, stream>>>(off, N);
        hist_kernel<<<(E + 255) / 256, 256, 0, stream>>>(ei, off, E);
        chunk_sums_kernel<<<NCHUNK, 256, 0, stream>>>(off, partials, N);
        scan_partials_kernel<<<1, 128, 0, stream>>>(partials, chunk_off, NCHUNK);
        scan_chunks_kernel<<<NCHUNK, 256, 0, stream>>>(off, chunk_off, N);
        fill_kernel<<<(E + 255) / 256, 256, 0, stream>>>(ei, off, dst_sorted, E);
        {
            long tot = (long)N * 32;
            convert_x_kernel<<<(int)((tot + 255) / 256), 256, 0, stream>>>(x, (char*)out, N);
        }
        gather_bf16_kernel<<<(N + 15) / 16, 256, 0, stream>>>(off, dst_sorted, (char*)out, N);
        gemm_mfma_kernel<<<(N + 127) / 128, 256, 0, stream>>>(W, Bm, out, N);
    }
}